// Round 2
// baseline (1068.119 us; speedup 1.0000x reference)
//
#include <hip/hip_runtime.h>
#include <hip/hip_bf16.h>
#include <math.h>

// Problem constants
#define NN 50000
#define PP 200000
#define LL 6
#define DD 128      // IN_DIM == OUT_DIM
#define HH 4        // heads

// Tiling
#define TM 32       // paths per workgroup (halved -> regs fit 4 waves/SIMD)
#define NT 512      // threads per workgroup (8 waves)
#define HPAD 132    // fp32 row stride for final-h LDS (bank spread)

typedef __attribute__((ext_vector_type(8))) short short8;   // 8 bf16 (MFMA A/B frag)
typedef __attribute__((ext_vector_type(4))) float f32x4;    // MFMA C/D frag

struct f3 { float x, y, z; };   // 12B packed, 4B-aligned (dwordx3)

__device__ __forceinline__ unsigned short f2bf(float v) {
    __hip_bfloat16 h = __float2bfloat16(v);
    return *(unsigned short*)&h;
}
__device__ __forceinline__ float bf2f(unsigned short u) {
    union { unsigned int i; float f; } c; c.i = ((unsigned int)u) << 16; return c.f;
}
__device__ __forceinline__ float fast_rcp(float x) { return __builtin_amdgcn_rcpf(x); }
__device__ __forceinline__ float fast_sigmoid(float x) {
    return fast_rcp(1.f + __expf(-x));
}
__device__ __forceinline__ float fast_tanh(float x) {
    float e = __expf(-2.f * fabsf(x));
    float t = (1.f - e) * fast_rcp(1.f + e);
    return copysignf(t, x);
}

// ---------------------------------------------------------------------------
// Prep: cast W_hh to bf16.
// ---------------------------------------------------------------------------
__global__ void prep_w_kernel(const float* __restrict__ w_hh,
                              unsigned short* __restrict__ whb) {
    int i = blockIdx.x * 256 + threadIdx.x;
    if (i < 3 * DD * DD) whb[i] = f2bf(w_hh[i]);
}

// ---------------------------------------------------------------------------
// Counting sort of paths by destination row (= path_list[p][5]).
// ---------------------------------------------------------------------------
__global__ void histo_kernel(const int* __restrict__ path_list,
                             int* __restrict__ cnt) {
    int p = blockIdx.x * 256 + threadIdx.x;
    if (p < PP) atomicAdd(&cnt[path_list[p * LL + (LL - 1)]], 1);
}

__global__ void scan_kernel(const int* __restrict__ cnt,
                            int* __restrict__ offs,
                            int* __restrict__ cursor) {
    __shared__ int ls[256];
    const int t = threadIdx.x;
    const int chunk = (NN + 255) / 256;
    int s = 0;
    for (int j = 0; j < chunk; ++j) {
        int i = t + j * 256;
        if (i < NN) s += cnt[i];
    }
    ls[t] = s; __syncthreads();
    for (int off = 1; off < 256; off <<= 1) {
        int v = (t >= off) ? ls[t - off] : 0;
        __syncthreads();
        ls[t] += v;
        __syncthreads();
    }
    int run = (t == 0) ? 0 : ls[t - 1];
    for (int j = 0; j < chunk; ++j) {
        int i = t + j * 256;
        if (i < NN) { offs[i] = run; cursor[i] = run; run += cnt[i]; }
    }
}

__global__ void scatter_kernel(const int* __restrict__ path_list,
                               int* __restrict__ cursor,
                               int* __restrict__ sorted) {
    int p = blockIdx.x * 256 + threadIdx.x;
    if (p < PP) {
        int row = path_list[p * LL + (LL - 1)];
        int k = atomicAdd(&cursor[row], 1);
        sorted[k] = p;
    }
}

// ---------------------------------------------------------------------------
// gi GEMM: gi[node][d][c] = x[node] @ W_ih[c*128+d] + biases (fused).
// Layout is [node][128][3] fp32 packed (12B per d) so the GRU kernel reads
// all 3 gates of (node,d) with ONE dwordx3 load.
// Wave w owns d = 16w+lcol; 3 gates per wave -> thread packs float3 writes
// (16 lanes x 12B = 192B contiguous per row).
// ---------------------------------------------------------------------------
__global__ __launch_bounds__(512, 2)
void gi_gemm_kernel(const float* __restrict__ x,     // [N][128]
                    const float* __restrict__ w_ih,  // [384][128]
                    const float* __restrict__ b_ih,
                    const float* __restrict__ b_hh,
                    float* __restrict__ gi)          // [N][128][3]
{
    const int tid  = threadIdx.x;
    const int lane = tid & 63;
    const int wave = tid >> 6;
    const int lcol = lane & 15;
    const int quad = lane >> 4;
    const int ko   = quad * 8;
    const int d    = wave * 16 + lcol;
    const int r0   = blockIdx.x * 64;

    short8 B[3][4];
    float bias[3];
    #pragma unroll
    for (int c = 0; c < 3; ++c) {
        int col = c * 128 + d;
        #pragma unroll
        for (int ks = 0; ks < 4; ++ks) {
            const float4* src = (const float4*)(w_ih + (size_t)col * 128 + ks * 32 + ko);
            float4 f0 = src[0], f1 = src[1];
            short8 b;
            b[0] = (short)f2bf(f0.x); b[1] = (short)f2bf(f0.y);
            b[2] = (short)f2bf(f0.z); b[3] = (short)f2bf(f0.w);
            b[4] = (short)f2bf(f1.x); b[5] = (short)f2bf(f1.y);
            b[6] = (short)f2bf(f1.z); b[7] = (short)f2bf(f1.w);
            B[c][ks] = b;
        }
        bias[c] = b_ih[col] + ((c < 2) ? b_hh[col] : 0.f);
    }

    f32x4 acc[3][4];
    #pragma unroll
    for (int c = 0; c < 3; ++c)
        #pragma unroll
        for (int rt = 0; rt < 4; ++rt)
            acc[c][rt] = (f32x4){bias[c], bias[c], bias[c], bias[c]};

    #pragma unroll
    for (int ks = 0; ks < 4; ++ks) {
        #pragma unroll
        for (int rt = 0; rt < 4; ++rt) {
            int row = r0 + rt * 16 + lcol;
            if (row >= NN) row = NN - 1;          // clamp loads, stores guarded
            const float4* src = (const float4*)(x + (size_t)row * 128 + ks * 32 + ko);
            float4 f0 = src[0], f1 = src[1];
            short8 av;
            av[0] = (short)f2bf(f0.x); av[1] = (short)f2bf(f0.y);
            av[2] = (short)f2bf(f0.z); av[3] = (short)f2bf(f0.w);
            av[4] = (short)f2bf(f1.x); av[5] = (short)f2bf(f1.y);
            av[6] = (short)f2bf(f1.z); av[7] = (short)f2bf(f1.w);
            acc[0][rt] = __builtin_amdgcn_mfma_f32_16x16x32_bf16(av, B[0][ks], acc[0][rt], 0, 0, 0);
            acc[1][rt] = __builtin_amdgcn_mfma_f32_16x16x32_bf16(av, B[1][ks], acc[1][rt], 0, 0, 0);
            acc[2][rt] = __builtin_amdgcn_mfma_f32_16x16x32_bf16(av, B[2][ks], acc[2][rt], 0, 0, 0);
        }
    }

    #pragma unroll
    for (int rt = 0; rt < 4; ++rt)
        #pragma unroll
        for (int rr = 0; rr < 4; ++rr) {
            int row = r0 + rt * 16 + quad * 4 + rr;
            if (row < NN) {
                float* o = gi + (size_t)row * 384 + d * 3;
                o[0] = acc[0][rt][rr];
                o[1] = acc[1][rt][rr];
                o[2] = acc[2][rt][rr];
            }
        }
}

// ---------------------------------------------------------------------------
// Pass A: h-side-only MFMA GRU, sized for 2 WGs/CU.
//  - TM=32 paths/WG, launch_bounds(512,4): regs <=128 -> 4 waves/SIMD ->
//    two independent workgroups per CU interleave their phases (load-wait of
//    one overlaps MFMA/VALU of the other) — attacks the 13k-cycle/step
//    phase-serialization wall seen in r0/r1.
//  - gi packed [node][d][3]: one 12B load per (path,d) instead of 3 scalars.
//  - hsb double-buffered, ONE barrier per step.
// ---------------------------------------------------------------------------
__global__ __launch_bounds__(NT, 4)
void gru_att_kernel(const float* __restrict__ gi,             // [N][128][3] fp32
                    const int*   __restrict__ path_list,
                    const unsigned short* __restrict__ whb,   // [384][128] bf16
                    const float* __restrict__ b_hh,
                    const float* __restrict__ a,              // [128][4]
                    float* __restrict__ att_sum,              // [N][4]
                    unsigned short* __restrict__ emb,         // [P][128] bf16
                    float* __restrict__ att_un_g)             // [P][4]
{
    // smem: [0,8192) hs0 | [8192,16384) hs1 | [16384,16896) pad
    //       hs_f fp32 (32*132*4 = 16896) aliases [0,16896)
    //       [16896,25088) red_s [32][16][4] | [25088,25856) nodes_s [TM*LL]
    __shared__ __align__(16) unsigned char smem[25856];
    unsigned short* hs0    = (unsigned short*)smem;
    unsigned short* hs1    = (unsigned short*)(smem + 8192);
    float*          hs_f   = (float*)smem;                 // alias (final step only)
    float*          red_s  = (float*)(smem + 16896);       // [32][16][4]
    int*            nodes_s= (int*)(smem + 25088);         // [TM*LL]

    const int tid  = threadIdx.x;
    const int lane = tid & 63;
    const int wave = tid >> 6;
    const int lcol = lane & 15;
    const int quad = lane >> 4;
    const int d    = wave * 16 + lcol;
    const int p0   = blockIdx.x * TM;
    const int ko   = quad * 8;

    // persistent h-side B fragments (c=0:r, 1:z, 2:n) — 48 VGPRs
    short8 Bh[3][4];
    #pragma unroll
    for (int c = 0; c < 3; ++c)
        #pragma unroll
        for (int ks = 0; ks < 4; ++ks)
            Bh[c][ks] = *(const short8*)(whb + (size_t)(c * DD + d) * DD + ks * 32 + ko);
    const float bhn = b_hh[d + 256];

    for (int i = tid; i < TM * LL; i += NT) nodes_s[i] = path_list[(size_t)p0 * LL + i];
    if (tid < TM * DD / 8)
        ((uint4*)hs0)[tid] = make_uint4(0u, 0u, 0u, 0u);

    float hreg[8];
    #pragma unroll
    for (int i = 0; i < 8; ++i) hreg[i] = 0.f;

    __syncthreads();   // nodes_s + hs0 zero visible

    #pragma unroll
    for (int t = 0; t < LL; ++t) {
        unsigned short* hr = (t & 1) ? hs1 : hs0;   // read buffer
        unsigned short* hw = (t & 1) ? hs0 : hs1;   // write buffer

        // gi loads (one dwordx3 per fragment row) -> accumulator init
        float gin[8];
        f32x4 accR[2], accZ[2], accH[2];
        #pragma unroll
        for (int rt = 0; rt < 2; ++rt)
            #pragma unroll
            for (int r = 0; r < 4; ++r) {
                const int p = rt * 16 + quad * 4 + r;
                const int node = nodes_s[p * LL + t];
                f3 g = *(const f3*)(gi + (size_t)node * 384 + d * 3);
                accR[rt][r] = g.x;        // ir + b_ih_r + b_hh_r
                accZ[rt][r] = g.y;        // iz + b_ih_z + b_hh_z
                gin[rt * 4 + r] = g.z;    // in + b_ih_n
            }
        #pragma unroll
        for (int rt = 0; rt < 2; ++rt)
            accH[rt] = (f32x4){bhn, bhn, bhn, bhn};

        // MFMA: h-side only (24 MFMAs, 8 ds_read_b128 per wave)
        #pragma unroll
        for (int ks = 0; ks < 4; ++ks) {
            const int kb = ks * 4 + quad;
            #pragma unroll
            for (int rt = 0; rt < 2; ++rt) {
                const int p = rt * 16 + lcol;
                short8 ah = *(const short8*)(hr + p * DD + ((kb ^ lcol) * 8));
                accR[rt] = __builtin_amdgcn_mfma_f32_16x16x32_bf16(ah, Bh[0][ks], accR[rt], 0, 0, 0);
                accZ[rt] = __builtin_amdgcn_mfma_f32_16x16x32_bf16(ah, Bh[1][ks], accZ[rt], 0, 0, 0);
                accH[rt] = __builtin_amdgcn_mfma_f32_16x16x32_bf16(ah, Bh[2][ks], accH[rt], 0, 0, 0);
            }
        }

        if (t == LL - 1) __syncthreads();  // hs_f aliases hs0/hs1: reads done first

        // GRU cell epilogue
        #pragma unroll
        for (int rt = 0; rt < 2; ++rt) {
            #pragma unroll
            for (int r = 0; r < 4; ++r) {
                const int idx = rt * 4 + r;
                const int p   = rt * 16 + quad * 4 + r;
                float rg = fast_sigmoid(accR[rt][r]);
                float zg = fast_sigmoid(accZ[rt][r]);
                float ng = fast_tanh(gin[idx] + rg * accH[rt][r]);  // accH = hn + b_hh_n
                float hnew = fmaf(zg, hreg[idx] - ng, ng);
                hreg[idx] = hnew;
                if (t < LL - 1) {
                    hw[p * DD + (((d >> 3) ^ (p & 15)) * 8) + (d & 7)] = f2bf(hnew);
                } else {
                    hs_f[p * HPAD + d] = hnew;   // fp32, aliases dead hs buffers
                }
            }
        }
        __syncthreads();   // hw complete (and, at t=5, hs_f complete)
    }

    // attention logits + emit bf16 path embedding
    // thread layout: pi = tid>>4 (path 0..31), tt = tid&15 (16 threads/row, 8 d each)
    {
        int pi = tid >> 4, tt = tid & 15;
        float s0 = 0.f, s1 = 0.f, s2 = 0.f, s3 = 0.f;
        unsigned short pack[8];
        #pragma unroll
        for (int j = 0; j < 8; ++j) {
            int dd2 = tt * 8 + j;
            float hv = hs_f[pi * HPAD + dd2];
            pack[j] = f2bf(hv);
            float4 av = *(const float4*)(a + dd2 * 4);
            s0 += hv * av.x; s1 += hv * av.y; s2 += hv * av.z; s3 += hv * av.w;
        }
        *(uint4*)(emb + (size_t)(p0 + pi) * DD + tt * 8) = *(uint4*)&pack[0];
        float* rp = red_s + (pi * 16 + tt) * 4;
        rp[0] = s0; rp[1] = s1; rp[2] = s2; rp[3] = s3;
    }
    __syncthreads();
    if (tid < TM) {
        int pi = tid;
        int row = nodes_s[pi * LL + (LL - 1)];
        float4 e4;
        #pragma unroll
        for (int h = 0; h < HH; ++h) {
            float s = 0.f;
            #pragma unroll
            for (int tt = 0; tt < 16; ++tt) s += red_s[(pi * 16 + tt) * 4 + h];
            float lv = (s > 0.f) ? s : 0.2f * s;
            float e  = __expf(lv);
            ((float*)&e4)[h] = e;
            atomicAdd(&att_sum[row * HH + h], e);
        }
        *(float4*)(att_un_g + (size_t)(p0 + pi) * HH) = e4;
    }
}

// ---------------------------------------------------------------------------
// Pass B: per-node aggregation over its sorted paths. Atomic-free.
// ---------------------------------------------------------------------------
__global__ __launch_bounds__(256)
void agg_kernel(const unsigned short* __restrict__ emb,   // [P][128] bf16
                const float* __restrict__ att_un,         // [P][4]
                const float* __restrict__ att_sum,        // [N][4]
                const int* __restrict__ offs,
                const int* __restrict__ cnt,
                const int* __restrict__ sorted,
                float* __restrict__ out)                  // [N][512]
{
    int node = blockIdx.x * 2 + (threadIdx.x >> 7);
    int d    = threadIdx.x & 127;
    if (node >= NN) return;
    int start = offs[node];
    int len   = cnt[node];
    float a0 = 0.f, a1 = 0.f, a2 = 0.f, a3 = 0.f;
    for (int i = 0; i < len; ++i) {
        int p = sorted[start + i];
        float4 at = *(const float4*)(att_un + (size_t)p * 4);
        float ev = bf2f(emb[(size_t)p * DD + d]);
        a0 = fmaf(at.x, ev, a0);
        a1 = fmaf(at.y, ev, a1);
        a2 = fmaf(at.z, ev, a2);
        a3 = fmaf(at.w, ev, a3);
    }
    float4 s = *(const float4*)(att_sum + (size_t)node * 4);
    float* o = out + (size_t)node * 512 + d;
    o[0]   = (s.x > 0.f) ? a0 / s.x : 0.f;
    o[128] = (s.y > 0.f) ? a1 / s.y : 0.f;
    o[256] = (s.z > 0.f) ? a2 / s.z : 0.f;
    o[384] = (s.w > 0.f) ? a3 / s.w : 0.f;
}

extern "C" void kernel_launch(void* const* d_in, const int* in_sizes, int n_in,
                              void* d_out, int out_size, void* d_ws, size_t ws_size,
                              hipStream_t stream) {
    const float* x         = (const float*)d_in[0];
    const int*   path_list = (const int*)  d_in[1];
    const float* w_ih      = (const float*)d_in[2];
    const float* w_hh      = (const float*)d_in[3];
    const float* b_ih      = (const float*)d_in[4];
    const float* b_hh      = (const float*)d_in[5];
    const float* a         = (const float*)d_in[6];
    float* out = (float*)d_out;

    // workspace layout (all 16B-multiple sizes), total ~133.5 MB
    char* w = (char*)d_ws;
    float*          att_sum = (float*)w;                 w += 800000;       // N*4 f32
    int*            cnt     = (int*)w;                   w += 200000;       // N
    int*            offs    = (int*)w;                   w += 200000;       // N
    int*            cursor  = (int*)w;                   w += 200000;       // N
    int*            sorted  = (int*)w;                   w += 800000;       // P
    float*          att_un  = (float*)w;                 w += 3200000;      // P*4 f32
    float*          gi      = (float*)w;                 w += 76800000;     // N*128*3 f32
    unsigned short* whb     = (unsigned short*)w;        w += 98304;        // 384*128 bf16
    unsigned short* emb     = (unsigned short*)w;        w += 51200000;     // P*128 bf16

    hipMemsetAsync(att_sum, 0, 800000, stream);
    hipMemsetAsync(cnt, 0, 200000, stream);

    prep_w_kernel<<<(3 * DD * DD + 255) / 256, 256, 0, stream>>>(w_hh, whb);

    histo_kernel<<<(PP + 255) / 256, 256, 0, stream>>>(path_list, cnt);
    scan_kernel<<<1, 256, 0, stream>>>(cnt, offs, cursor);
    scatter_kernel<<<(PP + 255) / 256, 256, 0, stream>>>(path_list, cursor, sorted);

    gi_gemm_kernel<<<(NN + 63) / 64, 512, 0, stream>>>(x, w_ih, b_ih, b_hh, gi);

    gru_att_kernel<<<PP / TM, NT, 0, stream>>>(gi, path_list, whb,
                                               b_hh, a, att_sum, emb, att_un);

    agg_kernel<<<(NN + 1) / 2, 256, 0, stream>>>(emb, att_un, att_sum,
                                                 offs, cnt, sorted, out);
}

// Round 3
// 779.592 us; speedup vs baseline: 1.3701x; 1.3701x over previous
//
#include <hip/hip_runtime.h>
#include <hip/hip_bf16.h>
#include <math.h>

// Problem constants
#define NN 50000
#define PP 200000
#define LL 6
#define DD 128      // IN_DIM == OUT_DIM
#define HH 4        // heads

// Tiling
#define TM 32       // paths per workgroup
#define NT 512      // threads per workgroup (8 waves)
#define HPAD 132    // fp32 row stride for final-h LDS (bank spread)

typedef __attribute__((ext_vector_type(8))) short short8;   // 8 bf16 (MFMA A/B frag)
typedef __attribute__((ext_vector_type(4))) float f32x4;    // MFMA C/D frag

struct f3 { float x, y, z; };   // 12B packed, 4B-aligned (dwordx3)

__device__ __forceinline__ unsigned short f2bf(float v) {
    __hip_bfloat16 h = __float2bfloat16(v);
    return *(unsigned short*)&h;
}
__device__ __forceinline__ float bf2f(unsigned short u) {
    union { unsigned int i; float f; } c; c.i = ((unsigned int)u) << 16; return c.f;
}
__device__ __forceinline__ float fast_rcp(float x) { return __builtin_amdgcn_rcpf(x); }
__device__ __forceinline__ float fast_sigmoid(float x) {
    return fast_rcp(1.f + __expf(-x));
}
__device__ __forceinline__ float fast_tanh(float x) {
    float e = __expf(-2.f * fabsf(x));
    float t = (1.f - e) * fast_rcp(1.f + e);
    return copysignf(t, x);
}

// ---------------------------------------------------------------------------
// Prep: cast W_hh to bf16.
// ---------------------------------------------------------------------------
__global__ void prep_w_kernel(const float* __restrict__ w_hh,
                              unsigned short* __restrict__ whb) {
    int i = blockIdx.x * 256 + threadIdx.x;
    if (i < 3 * DD * DD) whb[i] = f2bf(w_hh[i]);
}

// ---------------------------------------------------------------------------
// Counting sort of paths by destination row (= path_list[p][5]).
// ---------------------------------------------------------------------------
__global__ void histo_kernel(const int* __restrict__ path_list,
                             int* __restrict__ cnt) {
    int p = blockIdx.x * 256 + threadIdx.x;
    if (p < PP) atomicAdd(&cnt[path_list[p * LL + (LL - 1)]], 1);
}

__global__ void scan_kernel(const int* __restrict__ cnt,
                            int* __restrict__ offs,
                            int* __restrict__ cursor) {
    __shared__ int ls[256];
    const int t = threadIdx.x;
    const int chunk = (NN + 255) / 256;
    int s = 0;
    for (int j = 0; j < chunk; ++j) {
        int i = t + j * 256;
        if (i < NN) s += cnt[i];
    }
    ls[t] = s; __syncthreads();
    for (int off = 1; off < 256; off <<= 1) {
        int v = (t >= off) ? ls[t - off] : 0;
        __syncthreads();
        ls[t] += v;
        __syncthreads();
    }
    int run = (t == 0) ? 0 : ls[t - 1];
    for (int j = 0; j < chunk; ++j) {
        int i = t + j * 256;
        if (i < NN) { offs[i] = run; cursor[i] = run; run += cnt[i]; }
    }
}

__global__ void scatter_kernel(const int* __restrict__ path_list,
                               int* __restrict__ cursor,
                               int* __restrict__ sorted) {
    int p = blockIdx.x * 256 + threadIdx.x;
    if (p < PP) {
        int row = path_list[p * LL + (LL - 1)];
        int k = atomicAdd(&cursor[row], 1);
        sorted[k] = p;
    }
}

// ---------------------------------------------------------------------------
// gi GEMM: gi[node][d][c] = x[node] @ W_ih[c*128+d] + biases (fused).
// Layout [node][128][3] fp32 packed -> GRU reads all 3 gates of (node,d)
// with ONE dwordx3 load.
// ---------------------------------------------------------------------------
__global__ __launch_bounds__(512, 2)
void gi_gemm_kernel(const float* __restrict__ x,     // [N][128]
                    const float* __restrict__ w_ih,  // [384][128]
                    const float* __restrict__ b_ih,
                    const float* __restrict__ b_hh,
                    float* __restrict__ gi)          // [N][128][3]
{
    const int tid  = threadIdx.x;
    const int lane = tid & 63;
    const int wave = tid >> 6;
    const int lcol = lane & 15;
    const int quad = lane >> 4;
    const int ko   = quad * 8;
    const int d    = wave * 16 + lcol;
    const int r0   = blockIdx.x * 64;

    short8 B[3][4];
    float bias[3];
    #pragma unroll
    for (int c = 0; c < 3; ++c) {
        int col = c * 128 + d;
        #pragma unroll
        for (int ks = 0; ks < 4; ++ks) {
            const float4* src = (const float4*)(w_ih + (size_t)col * 128 + ks * 32 + ko);
            float4 f0 = src[0], f1 = src[1];
            short8 b;
            b[0] = (short)f2bf(f0.x); b[1] = (short)f2bf(f0.y);
            b[2] = (short)f2bf(f0.z); b[3] = (short)f2bf(f0.w);
            b[4] = (short)f2bf(f1.x); b[5] = (short)f2bf(f1.y);
            b[6] = (short)f2bf(f1.z); b[7] = (short)f2bf(f1.w);
            B[c][ks] = b;
        }
        bias[c] = b_ih[col] + ((c < 2) ? b_hh[col] : 0.f);
    }

    f32x4 acc[3][4];
    #pragma unroll
    for (int c = 0; c < 3; ++c)
        #pragma unroll
        for (int rt = 0; rt < 4; ++rt)
            acc[c][rt] = (f32x4){bias[c], bias[c], bias[c], bias[c]};

    #pragma unroll
    for (int ks = 0; ks < 4; ++ks) {
        #pragma unroll
        for (int rt = 0; rt < 4; ++rt) {
            int row = r0 + rt * 16 + lcol;
            if (row >= NN) row = NN - 1;          // clamp loads, stores guarded
            const float4* src = (const float4*)(x + (size_t)row * 128 + ks * 32 + ko);
            float4 f0 = src[0], f1 = src[1];
            short8 av;
            av[0] = (short)f2bf(f0.x); av[1] = (short)f2bf(f0.y);
            av[2] = (short)f2bf(f0.z); av[3] = (short)f2bf(f0.w);
            av[4] = (short)f2bf(f1.x); av[5] = (short)f2bf(f1.y);
            av[6] = (short)f2bf(f1.z); av[7] = (short)f2bf(f1.w);
            acc[0][rt] = __builtin_amdgcn_mfma_f32_16x16x32_bf16(av, B[0][ks], acc[0][rt], 0, 0, 0);
            acc[1][rt] = __builtin_amdgcn_mfma_f32_16x16x32_bf16(av, B[1][ks], acc[1][rt], 0, 0, 0);
            acc[2][rt] = __builtin_amdgcn_mfma_f32_16x16x32_bf16(av, B[2][ks], acc[2][rt], 0, 0, 0);
        }
    }

    #pragma unroll
    for (int rt = 0; rt < 4; ++rt)
        #pragma unroll
        for (int rr = 0; rr < 4; ++rr) {
            int row = r0 + rt * 16 + quad * 4 + rr;
            if (row < NN) {
                float* o = gi + (size_t)row * 384 + d * 3;
                o[0] = acc[0][rt][rr];
                o[1] = acc[1][rt][rr];
                o[2] = acc[2][rt][rr];
            }
        }
}

// ---------------------------------------------------------------------------
// Pass A: h-side-only MFMA GRU, 2 WGs/CU.
//  - TM=32, launch_bounds(512,4): cap 128 VGPR -> 4 waves/SIMD.
//  - t-loop NOT unrolled (r2's full unroll caused catastrophic spill:
//    VGPR 64 + 1.6 GB scratch traffic).
//  - gi issue-early/consume-late: loads issued at step start, acc init 0,
//    g.x/g.y added only in the epilogue after the MFMA phase -> gi L2/L3
//    latency hides under ds_read+MFMA instead of blocking the first MFMA.
//  - hsb double-buffered, ONE barrier per step.
// ---------------------------------------------------------------------------
__global__ __launch_bounds__(NT, 4)
void gru_att_kernel(const float* __restrict__ gi,             // [N][128][3] fp32
                    const int*   __restrict__ path_list,
                    const unsigned short* __restrict__ whb,   // [384][128] bf16
                    const float* __restrict__ b_hh,
                    const float* __restrict__ a,              // [128][4]
                    float* __restrict__ att_sum,              // [N][4]
                    unsigned short* __restrict__ emb,         // [P][128] bf16
                    float* __restrict__ att_un_g)             // [P][4]
{
    // smem: [0,8192) hs0 | [8192,16384) hs1 | [16384,16896) pad
    //       hs_f fp32 (32*132*4 = 16896) aliases [0,16896)
    //       [16896,25088) red_s [32][16][4] | [25088,25856) nodes_s [TM*LL]
    __shared__ __align__(16) unsigned char smem[25856];
    unsigned short* hs0    = (unsigned short*)smem;
    unsigned short* hs1    = (unsigned short*)(smem + 8192);
    float*          hs_f   = (float*)smem;                 // alias (final step only)
    float*          red_s  = (float*)(smem + 16896);       // [32][16][4]
    int*            nodes_s= (int*)(smem + 25088);         // [TM*LL]

    const int tid  = threadIdx.x;
    const int lane = tid & 63;
    const int wave = tid >> 6;
    const int lcol = lane & 15;
    const int quad = lane >> 4;
    const int d    = wave * 16 + lcol;
    const int p0   = blockIdx.x * TM;
    const int ko   = quad * 8;

    // persistent h-side B fragments (c=0:r, 1:z, 2:n) — 48 VGPRs
    short8 Bh[3][4];
    #pragma unroll
    for (int c = 0; c < 3; ++c)
        #pragma unroll
        for (int ks = 0; ks < 4; ++ks)
            Bh[c][ks] = *(const short8*)(whb + (size_t)(c * DD + d) * DD + ks * 32 + ko);
    const float bhn = b_hh[d + 256];

    for (int i = tid; i < TM * LL; i += NT) nodes_s[i] = path_list[(size_t)p0 * LL + i];
    if (tid < TM * DD / 8)
        ((uint4*)hs0)[tid] = make_uint4(0u, 0u, 0u, 0u);

    float hreg[8];
    #pragma unroll
    for (int i = 0; i < 8; ++i) hreg[i] = 0.f;

    __syncthreads();   // nodes_s + hs0 zero visible

    #pragma unroll 1
    for (int t = 0; t < LL; ++t) {
        unsigned short* hr = (t & 1) ? hs1 : hs0;   // read buffer
        unsigned short* hw = (t & 1) ? hs0 : hs1;   // write buffer

        // Issue gi loads NOW; consumed only in the epilogue (latency hidden
        // under the MFMA phase). Biases for r/z folded into gi by gi_gemm.
        f3 g[8];
        #pragma unroll
        for (int rt = 0; rt < 2; ++rt)
            #pragma unroll
            for (int r = 0; r < 4; ++r) {
                const int p = rt * 16 + quad * 4 + r;
                const int node = nodes_s[p * LL + t];
                g[rt * 4 + r] = *(const f3*)(gi + (size_t)node * 384 + d * 3);
            }

        f32x4 accR[2], accZ[2], accH[2];
        #pragma unroll
        for (int rt = 0; rt < 2; ++rt) {
            accR[rt] = (f32x4){0.f, 0.f, 0.f, 0.f};
            accZ[rt] = (f32x4){0.f, 0.f, 0.f, 0.f};
            accH[rt] = (f32x4){bhn, bhn, bhn, bhn};
        }

        // MFMA: h-side only (24 MFMAs, 8 ds_read_b128 per wave)
        #pragma unroll
        for (int ks = 0; ks < 4; ++ks) {
            const int kb = ks * 4 + quad;
            #pragma unroll
            for (int rt = 0; rt < 2; ++rt) {
                const int p = rt * 16 + lcol;
                short8 ah = *(const short8*)(hr + p * DD + ((kb ^ lcol) * 8));
                accR[rt] = __builtin_amdgcn_mfma_f32_16x16x32_bf16(ah, Bh[0][ks], accR[rt], 0, 0, 0);
                accZ[rt] = __builtin_amdgcn_mfma_f32_16x16x32_bf16(ah, Bh[1][ks], accZ[rt], 0, 0, 0);
                accH[rt] = __builtin_amdgcn_mfma_f32_16x16x32_bf16(ah, Bh[2][ks], accH[rt], 0, 0, 0);
            }
        }

        if (t == LL - 1) __syncthreads();  // hs_f aliases hs0/hs1: reads done first

        // GRU cell epilogue (gi consumed here — loads had the whole MFMA
        // phase to land)
        #pragma unroll
        for (int rt = 0; rt < 2; ++rt) {
            #pragma unroll
            for (int r = 0; r < 4; ++r) {
                const int idx = rt * 4 + r;
                const int p   = rt * 16 + quad * 4 + r;
                float rg = fast_sigmoid(accR[rt][r] + g[idx].x);
                float zg = fast_sigmoid(accZ[rt][r] + g[idx].y);
                float ng = fast_tanh(g[idx].z + rg * accH[rt][r]);  // accH = hn + b_hh_n
                float hnew = fmaf(zg, hreg[idx] - ng, ng);
                hreg[idx] = hnew;
                if (t < LL - 1) {
                    hw[p * DD + (((d >> 3) ^ (p & 15)) * 8) + (d & 7)] = f2bf(hnew);
                } else {
                    hs_f[p * HPAD + d] = hnew;   // fp32, aliases dead hs buffers
                }
            }
        }
        __syncthreads();   // hw complete (and, at t=5, hs_f complete)
    }

    // attention logits + emit bf16 path embedding
    // pi = tid>>4 (path 0..31), tt = tid&15 (16 threads/row, 8 d each)
    {
        int pi = tid >> 4, tt = tid & 15;
        float s0 = 0.f, s1 = 0.f, s2 = 0.f, s3 = 0.f;
        unsigned short pack[8];
        #pragma unroll
        for (int j = 0; j < 8; ++j) {
            int dd2 = tt * 8 + j;
            float hv = hs_f[pi * HPAD + dd2];
            pack[j] = f2bf(hv);
            float4 av = *(const float4*)(a + dd2 * 4);
            s0 += hv * av.x; s1 += hv * av.y; s2 += hv * av.z; s3 += hv * av.w;
        }
        *(uint4*)(emb + (size_t)(p0 + pi) * DD + tt * 8) = *(uint4*)&pack[0];
        float* rp = red_s + (pi * 16 + tt) * 4;
        rp[0] = s0; rp[1] = s1; rp[2] = s2; rp[3] = s3;
    }
    __syncthreads();
    if (tid < TM) {
        int pi = tid;
        int row = nodes_s[pi * LL + (LL - 1)];
        float4 e4;
        #pragma unroll
        for (int h = 0; h < HH; ++h) {
            float s = 0.f;
            #pragma unroll
            for (int tt = 0; tt < 16; ++tt) s += red_s[(pi * 16 + tt) * 4 + h];
            float lv = (s > 0.f) ? s : 0.2f * s;
            float e  = __expf(lv);
            ((float*)&e4)[h] = e;
            atomicAdd(&att_sum[row * HH + h], e);
        }
        *(float4*)(att_un_g + (size_t)(p0 + pi) * HH) = e4;
    }
}

// ---------------------------------------------------------------------------
// Pass B: per-node aggregation over its sorted paths. Atomic-free.
// ---------------------------------------------------------------------------
__global__ __launch_bounds__(256)
void agg_kernel(const unsigned short* __restrict__ emb,   // [P][128] bf16
                const float* __restrict__ att_un,         // [P][4]
                const float* __restrict__ att_sum,        // [N][4]
                const int* __restrict__ offs,
                const int* __restrict__ cnt,
                const int* __restrict__ sorted,
                float* __restrict__ out)                  // [N][512]
{
    int node = blockIdx.x * 2 + (threadIdx.x >> 7);
    int d    = threadIdx.x & 127;
    if (node >= NN) return;
    int start = offs[node];
    int len   = cnt[node];
    float a0 = 0.f, a1 = 0.f, a2 = 0.f, a3 = 0.f;
    for (int i = 0; i < len; ++i) {
        int p = sorted[start + i];
        float4 at = *(const float4*)(att_un + (size_t)p * 4);
        float ev = bf2f(emb[(size_t)p * DD + d]);
        a0 = fmaf(at.x, ev, a0);
        a1 = fmaf(at.y, ev, a1);
        a2 = fmaf(at.z, ev, a2);
        a3 = fmaf(at.w, ev, a3);
    }
    float4 s = *(const float4*)(att_sum + (size_t)node * 4);
    float* o = out + (size_t)node * 512 + d;
    o[0]   = (s.x > 0.f) ? a0 / s.x : 0.f;
    o[128] = (s.y > 0.f) ? a1 / s.y : 0.f;
    o[256] = (s.z > 0.f) ? a2 / s.z : 0.f;
    o[384] = (s.w > 0.f) ? a3 / s.w : 0.f;
}

extern "C" void kernel_launch(void* const* d_in, const int* in_sizes, int n_in,
                              void* d_out, int out_size, void* d_ws, size_t ws_size,
                              hipStream_t stream) {
    const float* x         = (const float*)d_in[0];
    const int*   path_list = (const int*)  d_in[1];
    const float* w_ih      = (const float*)d_in[2];
    const float* w_hh      = (const float*)d_in[3];
    const float* b_ih      = (const float*)d_in[4];
    const float* b_hh      = (const float*)d_in[5];
    const float* a         = (const float*)d_in[6];
    float* out = (float*)d_out;

    // workspace layout (all 16B-multiple sizes), total ~133.5 MB
    char* w = (char*)d_ws;
    float*          att_sum = (float*)w;                 w += 800000;       // N*4 f32
    int*            cnt     = (int*)w;                   w += 200000;       // N
    int*            offs    = (int*)w;                   w += 200000;       // N
    int*            cursor  = (int*)w;                   w += 200000;       // N
    int*            sorted  = (int*)w;                   w += 800000;       // P
    float*          att_un  = (float*)w;                 w += 3200000;      // P*4 f32
    float*          gi      = (float*)w;                 w += 76800000;     // N*128*3 f32
    unsigned short* whb     = (unsigned short*)w;        w += 98304;        // 384*128 bf16
    unsigned short* emb     = (unsigned short*)w;        w += 51200000;     // P*128 bf16

    hipMemsetAsync(att_sum, 0, 800000, stream);
    hipMemsetAsync(cnt, 0, 200000, stream);

    prep_w_kernel<<<(3 * DD * DD + 255) / 256, 256, 0, stream>>>(w_hh, whb);

    histo_kernel<<<(PP + 255) / 256, 256, 0, stream>>>(path_list, cnt);
    scan_kernel<<<1, 256, 0, stream>>>(cnt, offs, cursor);
    scatter_kernel<<<(PP + 255) / 256, 256, 0, stream>>>(path_list, cursor, sorted);

    gi_gemm_kernel<<<(NN + 63) / 64, 512, 0, stream>>>(x, w_ih, b_ih, b_hh, gi);

    gru_att_kernel<<<PP / TM, NT, 0, stream>>>(gi, path_list, whb,
                                               b_hh, a, att_sum, emb, att_un);

    agg_kernel<<<(NN + 1) / 2, 256, 0, stream>>>(emb, att_un, att_sum,
                                                 offs, cnt, sorted, out);
}